// Round 6
// baseline (30666.272 us; speedup 1.0000x reference)
//
#include <hip/hip_runtime.h>
#include <math.h>

#define B64   64
#define TT    512
#define U400  400
#define G1600 1600
#define NBPL  80            // blocks per layer
#define UPB   5             // units per block (20 gate-columns)
#define NCOL  (4 * UPB)
#define NW    8             // waves per block
#define NTHR  512
#define NBLK  (3 * NBPL)

// ---- device-coherent (sc1) access helpers: bypass L1/L2, served at L3 ----
__device__ __forceinline__ float ldg_c(const float* p) {
  return __hip_atomic_load(p, __ATOMIC_RELAXED, __HIP_MEMORY_SCOPE_AGENT);
}
__device__ __forceinline__ void stg_c(float* p, float v) {
  __hip_atomic_store(p, v, __ATOMIC_RELAXED, __HIP_MEMORY_SCOPE_AGENT);
}
__device__ __forceinline__ int adl(const unsigned* p) {
  return (int)__hip_atomic_load(p, __ATOMIC_RELAXED, __HIP_MEMORY_SCOPE_AGENT);
}

// x [64][512][3] -> xT [512][3][64]
__global__ void xpose_x_k(const float* __restrict__ x, float* __restrict__ xT) {
  int idx = blockIdx.x * 256 + threadIdx.x;
  if (idx < B64 * TT * 3) {
    int d = idx % 3;
    int t = (idx / 3) % TT;
    int b = idx / (3 * TT);
    xT[(t * 3 + d) * B64 + b] = x[idx];
  }
}

// generic tiled transpose: in R x C -> out C x R
__global__ void transpose_k(const float* __restrict__ in, float* __restrict__ out,
                            int R, int C) {
  __shared__ float tile[32][33];
  int bx = blockIdx.x * 32, by = blockIdx.y * 32;
  int tx = threadIdx.x, ty = threadIdx.y; // block (32,8)
  #pragma unroll
  for (int i = ty; i < 32; i += 8) {
    int r = by + i, c = bx + tx;
    if (r < R && c < C) tile[i][tx] = in[(size_t)r * C + c];
  }
  __syncthreads();
  #pragma unroll
  for (int i = ty; i < 32; i += 8) {
    int r = bx + i, c = by + tx;
    if (r < C && c < R) out[(size_t)r * R + c] = tile[tx][i];
  }
}

// K-slice GEMM with register double-buffered sc1 prefetch.
// CH loads in flight while CH*NCOL FMAs consume the previous chunk.
// All buf indices are compile-time (full unroll) -> stays in VGPRs.
template <int CH, int NCH>
__device__ __forceinline__ void gemm_slice(const float* __restrict__ aslab,
                                           int lane,
                                           const float* const (&wrow)[NCOL],
                                           float (&acc)[NCOL]) {
  float buf[2][CH];
  #pragma unroll
  for (int i = 0; i < CH; ++i)
    buf[0][i] = ldg_c(aslab + (size_t)i * B64 + lane);
  #pragma unroll
  for (int c = 0; c < NCH; ++c) {
    if (c + 1 < NCH) {
      #pragma unroll
      for (int i = 0; i < CH; ++i)
        buf[(c + 1) & 1][i] = ldg_c(aslab + (size_t)((c + 1) * CH + i) * B64 + lane);
    }
    #pragma unroll
    for (int i = 0; i < CH; ++i) {
      const float a = buf[c & 1][i];
      const int k = c * CH + i;
      #pragma unroll
      for (int cc = 0; cc < NCOL; ++cc) acc[cc] += a * wrow[cc][k];
    }
  }
}

struct ScanP {
  const float *xT0, *Wx0;
  const float *WxT1, *WxT2;
  const float *WhT0, *WhT1, *WhT2;
  const float *b0, *b1, *b2;
  const float *pi0, *pi1, *pi2;
  const float *pf0, *pf1, *pf2;
  const float *po0, *po1, *po2;
  float *h0r, *h1r;   // 8-slot rings [8][400][64]
  float *h2;          // full [512][400][64]
  unsigned *sync;     // [0..2] cnt per layer, [3..5] monotone arrive accumulators
};

// Persistent LSTM scan. Per-layer producer/consumer sync, per-wave waits,
// deep-prefetch GEMM. grid = 240 blocks (80/layer), 512 threads (8 waves).
__launch_bounds__(NTHR, 1)
__global__ void lstm_scan_k(ScanP p) {
  const int l    = blockIdx.x / NBPL;            // layer 0..2
  const int u0   = (blockIdx.x % NBPL) * UPB;    // first unit of this block
  const int lane = threadIdx.x & 63;
  const int kq   = __builtin_amdgcn_readfirstlane(threadIdx.x >> 6); // wave 0..7

  __shared__ float zs[NW][NCOL][B64];   // 40 KB partials

  const float* WhT  = (l == 0) ? p.WhT0 : (l == 1 ? p.WhT1 : p.WhT2);
  const float* WxT  = (l == 1) ? p.WxT1 : p.WxT2;      // unused for l==0
  const float* bias = (l == 0) ? p.b0  : (l == 1 ? p.b1  : p.b2);
  const float* pi   = (l == 0) ? p.pi0 : (l == 1 ? p.pi1 : p.pi2);
  const float* pf   = (l == 0) ? p.pf0 : (l == 1 ? p.pf1 : p.pf2);
  const float* po   = (l == 0) ? p.po0 : (l == 1 ? p.po1 : p.po2);
  const float* prevb = (l == 1) ? p.h0r : p.h1r;       // layer l-1 output ring
  float* ownb = (l == 0) ? p.h0r : (l == 1 ? p.h1r : p.h2);
  const int ownmask = (l == 2) ? (TT - 1) : 7;

  unsigned* cnt  = p.sync;       // [3] published step count per layer
  unsigned* acc_ = p.sync + 3;   // [3] monotone arrive accumulators

  // this wave's K-slice (wave-uniform)
  const float* wb; int k0, isH;
  if (l == 0)      { wb = WhT; k0 = kq * 50;        isH = 1; }
  else if (kq < 4) { wb = WxT; k0 = kq * 100;       isH = 0; }
  else             { wb = WhT; k0 = (kq - 4) * 100; isH = 1; }
  const bool isWx = (l > 0) && (kq < 4);

  const float* wrow[NCOL];
  #pragma unroll
  for (int g = 0; g < 4; ++g)
    #pragma unroll
    for (int uu = 0; uu < UPB; ++uu)
      wrow[g * UPB + uu] = wb + (size_t)(g * U400 + u0 + uu) * U400 + k0;

  float creg = 0.f;

  for (int t = 0; t < TT; ++t) {
    // ---- per-wave role-specific waits (all lanes spin; broadcast load) ----
    if (isWx) {
      while (adl(&cnt[l - 1]) < t + 1) __builtin_amdgcn_s_sleep(2);
    } else if (t > 0) {
      while (adl(&cnt[l]) < t) __builtin_amdgcn_s_sleep(2);
    }
    if (l < 2 && kq == NW - 1) {   // ring-slot-free (monotone -> early check safe)
      while (adl(&cnt[l + 1]) < t - 7) __builtin_amdgcn_s_sleep(2);
    }

    // ---- GEMM phase ----
    {
      float acc[NCOL];
      #pragma unroll
      for (int c = 0; c < NCOL; ++c) acc[c] = 0.f;

      if (!(isH && t == 0)) {
        const float* aslab = isH
            ? ownb  + (size_t)((t - 1) & ownmask) * (U400 * B64) + (size_t)k0 * B64
            : prevb + (size_t)(t & 7)             * (U400 * B64) + (size_t)k0 * B64;
        if (l == 0) gemm_slice<25, 2>(aslab, lane, wrow, acc);
        else        gemm_slice<25, 4>(aslab, lane, wrow, acc);
      }
      #pragma unroll
      for (int c = 0; c < NCOL; ++c) zs[kq][c][lane] = acc[c];
    }
    __syncthreads();   // zs visible to pointwise

    // ---- pointwise phase ----
    if (threadIdx.x < UPB * B64) {
      const int uu = threadIdx.x >> 6;
      const int b  = lane;
      const int u  = u0 + uu;
      float z0 = bias[0 * U400 + u], z1 = bias[1 * U400 + u];
      float z2 = bias[2 * U400 + u], z3 = bias[3 * U400 + u];
      #pragma unroll
      for (int w = 0; w < NW; ++w) {
        z0 += zs[w][0 * UPB + uu][b];
        z1 += zs[w][1 * UPB + uu][b];
        z2 += zs[w][2 * UPB + uu][b];
        z3 += zs[w][3 * UPB + uu][b];
      }
      if (l == 0) {
        #pragma unroll
        for (int dd = 0; dd < 3; ++dd) {
          float xv = p.xT0[(t * 3 + dd) * B64 + b];
          z0 += xv * p.Wx0[dd * G1600 + 0 * U400 + u];
          z1 += xv * p.Wx0[dd * G1600 + 1 * U400 + u];
          z2 += xv * p.Wx0[dd * G1600 + 2 * U400 + u];
          z3 += xv * p.Wx0[dd * G1600 + 3 * U400 + u];
        }
      }
      float cp = creg;
      float ig = 1.f / (1.f + expf(-(z0 + pi[u] * cp)));
      float fg = 1.f / (1.f + expf(-(z1 + pf[u] * cp)));
      float gg = tanhf(z2);
      float cn = fg * cp + ig * gg;
      float og = 1.f / (1.f + expf(-(z3 + po[u] * cn)));
      creg = cn;
      float h = og * tanhf(cn);
      stg_c(&ownb[(size_t)(t & ownmask) * (U400 * B64) + (size_t)u * B64 + b], h);
    }

    // drain: every wave's s_waitcnt vmcnt(0) before s_barrier -> all sc1
    // h-stores acked at the coherence point before the arrive RMW below.
    __syncthreads();

    // ---- arrive (monotone accumulator; no resets) ----
    if (threadIdx.x == 0) {
      unsigned old = __hip_atomic_fetch_add(&acc_[l], 1u, __ATOMIC_RELAXED,
                                            __HIP_MEMORY_SCOPE_AGENT);
      if (old == (unsigned)((t + 1) * NBPL - 1))
        __hip_atomic_store(&cnt[l], (unsigned)(t + 1), __ATOMIC_RELAXED,
                           __HIP_MEMORY_SCOPE_AGENT);
    }
  }
}

// out[b][t][f] = bd[f] + sum_u h2[t][u][b] * Wd[u][f]
__launch_bounds__(256)
__global__ void dense_k(const float* __restrict__ h2, const float* __restrict__ Wd,
                        const float* __restrict__ bd, float* __restrict__ out) {
  int wid  = blockIdx.x * 4 + (threadIdx.x >> 6);
  int lane = threadIdx.x & 63;
  int t = wid / 3, f = wid - t * 3;
  if (t >= TT) return;
  float acc = bd[f];
  const float* hrow = h2 + (size_t)t * U400 * B64 + lane;
  #pragma unroll 4
  for (int u = 0; u < U400; ++u) acc += hrow[(size_t)u * B64] * Wd[u * 3 + f];
  out[((size_t)lane * TT + t) * 3 + f] = acc;
}

extern "C" void kernel_launch(void* const* d_in, const int* in_sizes, int n_in,
                              void* d_out, int out_size, void* d_ws, size_t ws_size,
                              hipStream_t stream) {
  const float* x   = (const float*)d_in[0];
  const float* Wx0 = (const float*)d_in[1];
  const float* Wh0 = (const float*)d_in[2];
  const float* pi0 = (const float*)d_in[3];
  const float* pf0 = (const float*)d_in[4];
  const float* po0 = (const float*)d_in[5];
  const float* b0  = (const float*)d_in[6];
  const float* Wx1 = (const float*)d_in[7];
  const float* Wh1 = (const float*)d_in[8];
  const float* pi1 = (const float*)d_in[9];
  const float* pf1 = (const float*)d_in[10];
  const float* po1 = (const float*)d_in[11];
  const float* b1  = (const float*)d_in[12];
  const float* Wx2 = (const float*)d_in[13];
  const float* Wh2 = (const float*)d_in[14];
  const float* pi2 = (const float*)d_in[15];
  const float* pf2 = (const float*)d_in[16];
  const float* po2 = (const float*)d_in[17];
  const float* b2  = (const float*)d_in[18];
  const float* Wd  = (const float*)d_in[19];
  const float* bd  = (const float*)d_in[20];

  float* ws   = (float*)d_ws;
  float* xT0  = ws;                  // 98304
  float* WhT0 = xT0  + 98304;        // 640000 each
  float* WhT1 = WhT0 + 640000;
  float* WhT2 = WhT1 + 640000;
  float* WxT1 = WhT2 + 640000;
  float* WxT2 = WxT1 + 640000;
  float* h0r  = WxT2 + 640000;       // 8*400*64 = 204800
  float* h1r  = h0r  + 204800;       // 204800
  float* h2   = h1r  + 204800;       // 13107200
  unsigned* syn = (unsigned*)(h2 + 13107200);  // 6 counters

  hipMemsetAsync(syn, 0, 64, stream);

  hipLaunchKernelGGL(xpose_x_k, dim3(384), dim3(256), 0, stream, x, xT0);

  dim3 tb(32, 8);
  dim3 tg((G1600 + 31) / 32, (U400 + 31) / 32);
  hipLaunchKernelGGL(transpose_k, tg, tb, 0, stream, Wh0, WhT0, U400, G1600);
  hipLaunchKernelGGL(transpose_k, tg, tb, 0, stream, Wh1, WhT1, U400, G1600);
  hipLaunchKernelGGL(transpose_k, tg, tb, 0, stream, Wh2, WhT2, U400, G1600);
  hipLaunchKernelGGL(transpose_k, tg, tb, 0, stream, Wx1, WxT1, U400, G1600);
  hipLaunchKernelGGL(transpose_k, tg, tb, 0, stream, Wx2, WxT2, U400, G1600);

  ScanP hp;
  hp.xT0 = xT0;  hp.Wx0 = Wx0;
  hp.WxT1 = WxT1; hp.WxT2 = WxT2;
  hp.WhT0 = WhT0; hp.WhT1 = WhT1; hp.WhT2 = WhT2;
  hp.b0 = b0; hp.b1 = b1; hp.b2 = b2;
  hp.pi0 = pi0; hp.pi1 = pi1; hp.pi2 = pi2;
  hp.pf0 = pf0; hp.pf1 = pf1; hp.pf2 = pf2;
  hp.po0 = po0; hp.po1 = po1; hp.po2 = po2;
  hp.h0r = h0r; hp.h1r = h1r; hp.h2 = h2;
  hp.sync = syn;

  // cooperative launch only for the co-residency guarantee (no grid.sync used)
  void* args[] = { &hp };
  hipLaunchCooperativeKernel((void*)lstm_scan_k, dim3(NBLK), dim3(NTHR),
                             args, 0, stream);

  hipLaunchKernelGGL(dense_k, dim3(384), dim3(256), 0, stream, h2, Wd, bd,
                     (float*)d_out);
}

// Round 7
// 28890.649 us; speedup vs baseline: 1.0615x; 1.0615x over previous
//
#include <hip/hip_runtime.h>
#include <math.h>

#define B64   64
#define TT    512
#define U400  400
#define G1600 1600
#define NBPL  80            // blocks per layer
#define UPB   5             // units per block (20 gate-columns)
#define NCOL  (4 * UPB)
#define NW    16            // waves per block
#define NTHR  1024
#define NBLK  (3 * NBPL)

// ---- device-coherent (sc1) access helpers: bypass L1/L2, served at L3 ----
__device__ __forceinline__ float ldg_c(const float* p) {
  return __hip_atomic_load(p, __ATOMIC_RELAXED, __HIP_MEMORY_SCOPE_AGENT);
}
__device__ __forceinline__ void stg_c(float* p, float v) {
  __hip_atomic_store(p, v, __ATOMIC_RELAXED, __HIP_MEMORY_SCOPE_AGENT);
}
__device__ __forceinline__ int adl(const unsigned* p) {
  return (int)__hip_atomic_load(p, __ATOMIC_RELAXED, __HIP_MEMORY_SCOPE_AGENT);
}

// x [64][512][3] -> xT [512][3][64]
__global__ void xpose_x_k(const float* __restrict__ x, float* __restrict__ xT) {
  int idx = blockIdx.x * 256 + threadIdx.x;
  if (idx < B64 * TT * 3) {
    int d = idx % 3;
    int t = (idx / 3) % TT;
    int b = idx / (3 * TT);
    xT[(t * 3 + d) * B64 + b] = x[idx];
  }
}

// generic tiled transpose: in R x C -> out C x R
__global__ void transpose_k(const float* __restrict__ in, float* __restrict__ out,
                            int R, int C) {
  __shared__ float tile[32][33];
  int bx = blockIdx.x * 32, by = blockIdx.y * 32;
  int tx = threadIdx.x, ty = threadIdx.y; // block (32,8)
  #pragma unroll
  for (int i = ty; i < 32; i += 8) {
    int r = by + i, c = bx + tx;
    if (r < R && c < C) tile[i][tx] = in[(size_t)r * C + c];
  }
  __syncthreads();
  #pragma unroll
  for (int i = ty; i < 32; i += 8) {
    int r = bx + i, c = by + tx;
    if (r < C && c < R) out[(size_t)r * R + c] = tile[tx][i];
  }
}

// K-slice GEMM, register double-buffered sc1 prefetch, lean VGPR budget.
// wk = weight base + k0 (wave-uniform -> scalar address stream).
// All indices compile-time -> buf/acc stay in VGPRs.
template <int CH, int NCH>
__device__ __forceinline__ void gemm_slice(const float* __restrict__ aslab,
                                           int lane, int u0,
                                           const float* __restrict__ wk,
                                           float* __restrict__ acc) {
  float buf[2][CH];
  #pragma unroll
  for (int i = 0; i < CH; ++i)
    buf[0][i] = ldg_c(aslab + (size_t)i * B64 + lane);
  #pragma unroll
  for (int c = 0; c < NCH; ++c) {
    if (c + 1 < NCH) {
      #pragma unroll
      for (int i = 0; i < CH; ++i)
        buf[(c + 1) & 1][i] =
            ldg_c(aslab + (size_t)((c + 1) * CH + i) * B64 + lane);
    }
    #pragma unroll
    for (int i = 0; i < CH; ++i) {
      const float a = buf[c & 1][i];
      #pragma unroll
      for (int g = 0; g < 4; ++g)
        #pragma unroll
        for (int uu = 0; uu < UPB; ++uu)
          acc[g * UPB + uu] +=
              a * wk[(size_t)(g * U400 + u0 + uu) * U400 + c * CH + i];
    }
  }
}

struct ScanP {
  const float *xT0, *Wx0;
  const float *WxT1, *WxT2;
  const float *WhT0, *WhT1, *WhT2;
  const float *b0, *b1, *b2;
  const float *pi0, *pi1, *pi2;
  const float *pf0, *pf1, *pf2;
  const float *po0, *po1, *po2;
  float *h0r, *h1r;   // 8-slot rings [8][400][64]
  float *h2;          // full [512][400][64]
  unsigned *sync;     // [0..2] cnt per layer, [3..5] monotone arrive accumulators
};

// Persistent LSTM scan. Per-layer producer/consumer sync, per-wave waits.
// grid = 240 blocks (80/layer), block = 1024 threads (16 waves):
// 16 waves/CU latency hiding, K-slice 50 (l>0) / 25 (l=0) per wave.
__launch_bounds__(NTHR, 4)
__global__ void lstm_scan_k(ScanP p) {
  const int l    = blockIdx.x / NBPL;            // layer 0..2
  const int u0   = (blockIdx.x % NBPL) * UPB;    // first unit of this block
  const int lane = threadIdx.x & 63;
  const int kq   = __builtin_amdgcn_readfirstlane(threadIdx.x >> 6); // wave 0..15

  __shared__ float zs[NW][NCOL][B64];   // 80 KB partials

  const float* WhT  = (l == 0) ? p.WhT0 : (l == 1 ? p.WhT1 : p.WhT2);
  const float* WxT  = (l == 1) ? p.WxT1 : p.WxT2;      // unused for l==0
  const float* bias = (l == 0) ? p.b0  : (l == 1 ? p.b1  : p.b2);
  const float* pi   = (l == 0) ? p.pi0 : (l == 1 ? p.pi1 : p.pi2);
  const float* pf   = (l == 0) ? p.pf0 : (l == 1 ? p.pf1 : p.pf2);
  const float* po   = (l == 0) ? p.po0 : (l == 1 ? p.po1 : p.po2);
  const float* prevb = (l == 1) ? p.h0r : p.h1r;       // layer l-1 output ring
  float* ownb = (l == 0) ? p.h0r : (l == 1 ? p.h1r : p.h2);
  const int ownmask = (l == 2) ? (TT - 1) : 7;

  unsigned* cnt  = p.sync;       // [3] published step count per layer
  unsigned* acc_ = p.sync + 3;   // [3] monotone arrive accumulators

  // this wave's K-slice (wave-uniform)
  const float* wb; int k0, isH;
  if (l == 0)      { wb = WhT; k0 = kq * 25;        isH = 1; }
  else if (kq < 8) { wb = WxT; k0 = kq * 50;        isH = 0; }
  else             { wb = WhT; k0 = (kq - 8) * 50;  isH = 1; }
  const bool isWx = (l > 0) && (kq < 8);
  const float* wk = wb + k0;     // wave-uniform weight base

  float creg = 0.f;

  for (int t = 0; t < TT; ++t) {
    // ---- per-wave role-specific waits ----
    if (isWx) {
      while (adl(&cnt[l - 1]) < t + 1) __builtin_amdgcn_s_sleep(2);
    } else if (t > 0) {
      while (adl(&cnt[l]) < t) __builtin_amdgcn_s_sleep(2);
    }
    if (l < 2 && kq == NW - 1) {   // ring-slot-free (monotone -> early check safe)
      while (adl(&cnt[l + 1]) < t - 7) __builtin_amdgcn_s_sleep(2);
    }

    // ---- GEMM phase ----
    {
      float acc[NCOL];
      #pragma unroll
      for (int c = 0; c < NCOL; ++c) acc[c] = 0.f;

      if (!(isH && t == 0)) {
        const float* aslab = isH
            ? ownb  + (size_t)((t - 1) & ownmask) * (U400 * B64) + (size_t)k0 * B64
            : prevb + (size_t)(t & 7)             * (U400 * B64) + (size_t)k0 * B64;
        if (l == 0) gemm_slice<5, 5>(aslab, lane, u0, wk, acc);
        else        gemm_slice<10, 5>(aslab, lane, u0, wk, acc);
      }
      #pragma unroll
      for (int c = 0; c < NCOL; ++c) zs[kq][c][lane] = acc[c];
    }
    __syncthreads();   // zs visible to pointwise

    // ---- pointwise phase ----
    if (threadIdx.x < UPB * B64) {
      const int uu = threadIdx.x >> 6;
      const int b  = lane;
      const int u  = u0 + uu;
      float z0 = bias[0 * U400 + u], z1 = bias[1 * U400 + u];
      float z2 = bias[2 * U400 + u], z3 = bias[3 * U400 + u];
      #pragma unroll
      for (int w = 0; w < NW; ++w) {
        z0 += zs[w][0 * UPB + uu][b];
        z1 += zs[w][1 * UPB + uu][b];
        z2 += zs[w][2 * UPB + uu][b];
        z3 += zs[w][3 * UPB + uu][b];
      }
      if (l == 0) {
        #pragma unroll
        for (int dd = 0; dd < 3; ++dd) {
          float xv = p.xT0[(t * 3 + dd) * B64 + b];
          z0 += xv * p.Wx0[dd * G1600 + 0 * U400 + u];
          z1 += xv * p.Wx0[dd * G1600 + 1 * U400 + u];
          z2 += xv * p.Wx0[dd * G1600 + 2 * U400 + u];
          z3 += xv * p.Wx0[dd * G1600 + 3 * U400 + u];
        }
      }
      float cp = creg;
      float ig = 1.f / (1.f + expf(-(z0 + pi[u] * cp)));
      float fg = 1.f / (1.f + expf(-(z1 + pf[u] * cp)));
      float gg = tanhf(z2);
      float cn = fg * cp + ig * gg;
      float og = 1.f / (1.f + expf(-(z3 + po[u] * cn)));
      creg = cn;
      float h = og * tanhf(cn);
      stg_c(&ownb[(size_t)(t & ownmask) * (U400 * B64) + (size_t)u * B64 + b], h);
    }

    // drain: every wave's s_waitcnt vmcnt(0) before s_barrier -> all sc1
    // h-stores acked at the coherence point before the arrive RMW below.
    __syncthreads();

    // ---- arrive (monotone accumulator; no resets) ----
    if (threadIdx.x == 0) {
      unsigned old = __hip_atomic_fetch_add(&acc_[l], 1u, __ATOMIC_RELAXED,
                                            __HIP_MEMORY_SCOPE_AGENT);
      if (old == (unsigned)((t + 1) * NBPL - 1))
        __hip_atomic_store(&cnt[l], (unsigned)(t + 1), __ATOMIC_RELAXED,
                           __HIP_MEMORY_SCOPE_AGENT);
    }
  }
}

// out[b][t][f] = bd[f] + sum_u h2[t][u][b] * Wd[u][f]
__launch_bounds__(256)
__global__ void dense_k(const float* __restrict__ h2, const float* __restrict__ Wd,
                        const float* __restrict__ bd, float* __restrict__ out) {
  int wid  = blockIdx.x * 4 + (threadIdx.x >> 6);
  int lane = threadIdx.x & 63;
  int t = wid / 3, f = wid - t * 3;
  if (t >= TT) return;
  float acc = bd[f];
  const float* hrow = h2 + (size_t)t * U400 * B64 + lane;
  #pragma unroll 4
  for (int u = 0; u < U400; ++u) acc += hrow[(size_t)u * B64] * Wd[u * 3 + f];
  out[((size_t)lane * TT + t) * 3 + f] = acc;
}

extern "C" void kernel_launch(void* const* d_in, const int* in_sizes, int n_in,
                              void* d_out, int out_size, void* d_ws, size_t ws_size,
                              hipStream_t stream) {
  const float* x   = (const float*)d_in[0];
  const float* Wx0 = (const float*)d_in[1];
  const float* Wh0 = (const float*)d_in[2];
  const float* pi0 = (const float*)d_in[3];
  const float* pf0 = (const float*)d_in[4];
  const float* po0 = (const float*)d_in[5];
  const float* b0  = (const float*)d_in[6];
  const float* Wx1 = (const float*)d_in[7];
  const float* Wh1 = (const float*)d_in[8];
  const float* pi1 = (const float*)d_in[9];
  const float* pf1 = (const float*)d_in[10];
  const float* po1 = (const float*)d_in[11];
  const float* b1  = (const float*)d_in[12];
  const float* Wx2 = (const float*)d_in[13];
  const float* Wh2 = (const float*)d_in[14];
  const float* pi2 = (const float*)d_in[15];
  const float* pf2 = (const float*)d_in[16];
  const float* po2 = (const float*)d_in[17];
  const float* b2  = (const float*)d_in[18];
  const float* Wd  = (const float*)d_in[19];
  const float* bd  = (const float*)d_in[20];

  float* ws   = (float*)d_ws;
  float* xT0  = ws;                  // 98304
  float* WhT0 = xT0  + 98304;        // 640000 each
  float* WhT1 = WhT0 + 640000;
  float* WhT2 = WhT1 + 640000;
  float* WxT1 = WhT2 + 640000;
  float* WxT2 = WxT1 + 640000;
  float* h0r  = WxT2 + 640000;       // 8*400*64 = 204800
  float* h1r  = h0r  + 204800;       // 204800
  float* h2   = h1r  + 204800;       // 13107200
  unsigned* syn = (unsigned*)(h2 + 13107200);  // 6 counters

  hipMemsetAsync(syn, 0, 64, stream);

  hipLaunchKernelGGL(xpose_x_k, dim3(384), dim3(256), 0, stream, x, xT0);

  dim3 tb(32, 8);
  dim3 tg((G1600 + 31) / 32, (U400 + 31) / 32);
  hipLaunchKernelGGL(transpose_k, tg, tb, 0, stream, Wh0, WhT0, U400, G1600);
  hipLaunchKernelGGL(transpose_k, tg, tb, 0, stream, Wh1, WhT1, U400, G1600);
  hipLaunchKernelGGL(transpose_k, tg, tb, 0, stream, Wh2, WhT2, U400, G1600);
  hipLaunchKernelGGL(transpose_k, tg, tb, 0, stream, Wx1, WxT1, U400, G1600);
  hipLaunchKernelGGL(transpose_k, tg, tb, 0, stream, Wx2, WxT2, U400, G1600);

  ScanP hp;
  hp.xT0 = xT0;  hp.Wx0 = Wx0;
  hp.WxT1 = WxT1; hp.WxT2 = WxT2;
  hp.WhT0 = WhT0; hp.WhT1 = WhT1; hp.WhT2 = WhT2;
  hp.b0 = b0; hp.b1 = b1; hp.b2 = b2;
  hp.pi0 = pi0; hp.pi1 = pi1; hp.pi2 = pi2;
  hp.pf0 = pf0; hp.pf1 = pf1; hp.pf2 = pf2;
  hp.po0 = po0; hp.po1 = po1; hp.po2 = po2;
  hp.h0r = h0r; hp.h1r = h1r; hp.h2 = h2;
  hp.sync = syn;

  // cooperative launch only for the co-residency guarantee (no grid.sync used)
  void* args[] = { &hp };
  hipLaunchCooperativeKernel((void*)lstm_scan_k, dim3(NBLK), dim3(NTHR),
                             args, 0, stream);

  hipLaunchKernelGGL(dense_k, dim3(384), dim3(256), 0, stream, h2, Wd, bd,
                     (float*)d_out);
}

// Round 8
// 21496.423 us; speedup vs baseline: 1.4266x; 1.3440x over previous
//
#include <hip/hip_runtime.h>
#include <math.h>

#define B64   64
#define TT    512
#define U400  400
#define G1600 1600
#define NBPL  80            // blocks per layer
#define UPB   5             // units per block (20 gate-columns)
#define NCOL  (4 * UPB)
#define NW    8             // waves per block
#define NTHR  512
#define NBLK  (3 * NBPL)

// ---- device-coherent access helpers: bypass L1/L2, served at L3 ----
__device__ __forceinline__ float ldg_c(const float* p) {
  return __hip_atomic_load(p, __ATOMIC_RELAXED, __HIP_MEMORY_SCOPE_AGENT);
}
__device__ __forceinline__ void stg_c(float* p, float v) {
  __hip_atomic_store(p, v, __ATOMIC_RELAXED, __HIP_MEMORY_SCOPE_AGENT);
}
__device__ __forceinline__ int adl(const unsigned* p) {
  return (int)__hip_atomic_load(p, __ATOMIC_RELAXED, __HIP_MEMORY_SCOPE_AGENT);
}

// x [64][512][3] -> xT [512][3][64]
__global__ void xpose_x_k(const float* __restrict__ x, float* __restrict__ xT) {
  int idx = blockIdx.x * 256 + threadIdx.x;
  if (idx < B64 * TT * 3) {
    int d = idx % 3;
    int t = (idx / 3) % TT;
    int b = idx / (3 * TT);
    xT[(t * 3 + d) * B64 + b] = x[idx];
  }
}

// generic tiled transpose: in R x C -> out C x R
__global__ void transpose_k(const float* __restrict__ in, float* __restrict__ out,
                            int R, int C) {
  __shared__ float tile[32][33];
  int bx = blockIdx.x * 32, by = blockIdx.y * 32;
  int tx = threadIdx.x, ty = threadIdx.y; // block (32,8)
  #pragma unroll
  for (int i = ty; i < 32; i += 8) {
    int r = by + i, c = bx + tx;
    if (r < R && c < C) tile[i][tx] = in[(size_t)r * C + c];
  }
  __syncthreads();
  #pragma unroll
  for (int i = ty; i < 32; i += 8) {
    int r = bx + i, c = by + tx;
    if (r < C && c < R) out[(size_t)r * R + c] = tile[tx][i];
  }
}

// K-slice GEMM over NQ quads of k. Activations: 4 independent L3 loads per
// quad, unroll 4 => ~16 in flight. Weights: one float4 broadcast load per
// (col, quad) from L1/L2 feeding 4 FMAs. acc stays in VGPRs (array ref).
template <int NQ>
__device__ __forceinline__ void gemm_q(const float* __restrict__ aslab,
                                       int lane,
                                       const float* __restrict__ wg0,
                                       const float* __restrict__ wg1,
                                       const float* __restrict__ wg2,
                                       const float* __restrict__ wg3,
                                       float (&acc)[NCOL]) {
  #pragma unroll 4
  for (int q = 0; q < NQ; ++q) {
    const float a0 = ldg_c(aslab + (size_t)(4 * q + 0) * B64 + lane);
    const float a1 = ldg_c(aslab + (size_t)(4 * q + 1) * B64 + lane);
    const float a2 = ldg_c(aslab + (size_t)(4 * q + 2) * B64 + lane);
    const float a3 = ldg_c(aslab + (size_t)(4 * q + 3) * B64 + lane);
    #pragma unroll
    for (int uu = 0; uu < UPB; ++uu) {
      const float4 w = *reinterpret_cast<const float4*>(wg0 + uu * U400 + 4 * q);
      acc[0 * UPB + uu] += a0 * w.x + a1 * w.y + a2 * w.z + a3 * w.w;
    }
    #pragma unroll
    for (int uu = 0; uu < UPB; ++uu) {
      const float4 w = *reinterpret_cast<const float4*>(wg1 + uu * U400 + 4 * q);
      acc[1 * UPB + uu] += a0 * w.x + a1 * w.y + a2 * w.z + a3 * w.w;
    }
    #pragma unroll
    for (int uu = 0; uu < UPB; ++uu) {
      const float4 w = *reinterpret_cast<const float4*>(wg2 + uu * U400 + 4 * q);
      acc[2 * UPB + uu] += a0 * w.x + a1 * w.y + a2 * w.z + a3 * w.w;
    }
    #pragma unroll
    for (int uu = 0; uu < UPB; ++uu) {
      const float4 w = *reinterpret_cast<const float4*>(wg3 + uu * U400 + 4 * q);
      acc[3 * UPB + uu] += a0 * w.x + a1 * w.y + a2 * w.z + a3 * w.w;
    }
  }
}

struct ScanP {
  const float *xT0, *Wx0;
  const float *WxT1, *WxT2;
  const float *WhT0, *WhT1, *WhT2;
  const float *b0, *b1, *b2;
  const float *pi0, *pi1, *pi2;
  const float *pf0, *pf1, *pf2;
  const float *po0, *po1, *po2;
  float *h0r, *h1r;   // 8-slot rings [8][400][64]
  float *h2;          // full [512][400][64]
  unsigned *sync;     // [0..2] cnt per layer, [3..5] monotone arrive accumulators
};

// Persistent LSTM scan. Per-layer producer/consumer counters, no fences.
// grid = 240 blocks (80/layer), block = 512 threads (8 waves).
// Waves split K: l=0 -> {52,52,52,52,48,48,48,48} of own h;
// l>0 -> kq<4: 100 of prev-layer h (Wx), kq>=4: 100 of own h (Wh).
__launch_bounds__(NTHR, 1)
__global__ void lstm_scan_k(ScanP p) {
  const int l    = blockIdx.x / NBPL;            // layer 0..2
  const int u0   = (blockIdx.x % NBPL) * UPB;    // first unit of this block
  const int lane = threadIdx.x & 63;
  const int kq   = __builtin_amdgcn_readfirstlane(threadIdx.x >> 6); // wave 0..7

  __shared__ float zs[NW][NCOL][B64];   // 40 KB partials

  const float* WhT  = (l == 0) ? p.WhT0 : (l == 1 ? p.WhT1 : p.WhT2);
  const float* WxT  = (l == 1) ? p.WxT1 : p.WxT2;      // unused for l==0
  const float* bias = (l == 0) ? p.b0  : (l == 1 ? p.b1  : p.b2);
  const float* pi   = (l == 0) ? p.pi0 : (l == 1 ? p.pi1 : p.pi2);
  const float* pf   = (l == 0) ? p.pf0 : (l == 1 ? p.pf1 : p.pf2);
  const float* po   = (l == 0) ? p.po0 : (l == 1 ? p.po1 : p.po2);
  const float* prevb = (l == 1) ? p.h0r : p.h1r;       // layer l-1 output ring
  float* ownb = (l == 0) ? p.h0r : (l == 1 ? p.h1r : p.h2);
  const int ownmask = (l == 2) ? (TT - 1) : 7;

  unsigned* cnt  = p.sync;       // [3] published step count per layer
  unsigned* acc_ = p.sync + 3;   // [3] monotone arrive accumulators

  // this wave's K-slice (wave-uniform; k0 always a multiple of 4)
  const float* wb; int k0, isH;
  if (l == 0) {
    wb = WhT; isH = 1;
    k0 = (kq < 4) ? kq * 52 : 208 + (kq - 4) * 48;
  } else if (kq < 4) {
    wb = WxT; isH = 0; k0 = kq * 100;
  } else {
    wb = WhT; isH = 1; k0 = (kq - 4) * 100;
  }

  const float* wg0 = wb + (size_t)(0 * U400 + u0) * U400 + k0;
  const float* wg1 = wb + (size_t)(1 * U400 + u0) * U400 + k0;
  const float* wg2 = wb + (size_t)(2 * U400 + u0) * U400 + k0;
  const float* wg3 = wb + (size_t)(3 * U400 + u0) * U400 + k0;

  float creg = 0.f;

  for (int t = 0; t < TT; ++t) {
    // ---- wait phase (thread 0 spins on device-coherent counters) ----
    if (threadIdx.x == 0) {
      while (adl(&cnt[l]) < t) __builtin_amdgcn_s_sleep(1);
      if (l > 0)
        while (adl(&cnt[l - 1]) < t + 1) __builtin_amdgcn_s_sleep(1);
      if (l < 2)
        while (adl(&cnt[l + 1]) < t - 7) __builtin_amdgcn_s_sleep(1);
    }
    __syncthreads();

    // ---- GEMM phase ----
    {
      float acc[NCOL];
      #pragma unroll
      for (int c = 0; c < NCOL; ++c) acc[c] = 0.f;

      if (!(isH && t == 0)) {
        const float* aslab = isH
            ? ownb  + (size_t)((t - 1) & ownmask) * (U400 * B64) + (size_t)k0 * B64
            : prevb + (size_t)(t & 7)             * (U400 * B64) + (size_t)k0 * B64;
        if (l == 0) {
          if (kq < 4) gemm_q<13>(aslab, lane, wg0, wg1, wg2, wg3, acc);
          else        gemm_q<12>(aslab, lane, wg0, wg1, wg2, wg3, acc);
        } else {
          gemm_q<25>(aslab, lane, wg0, wg1, wg2, wg3, acc);
        }
      }
      #pragma unroll
      for (int c = 0; c < NCOL; ++c) zs[kq][c][lane] = acc[c];
    }
    __syncthreads();   // zs visible to pointwise

    // ---- pointwise phase ----
    if (threadIdx.x < UPB * B64) {
      const int uu = threadIdx.x >> 6;
      const int b  = lane;
      const int u  = u0 + uu;
      float z0 = bias[0 * U400 + u], z1 = bias[1 * U400 + u];
      float z2 = bias[2 * U400 + u], z3 = bias[3 * U400 + u];
      #pragma unroll
      for (int w = 0; w < NW; ++w) {
        z0 += zs[w][0 * UPB + uu][b];
        z1 += zs[w][1 * UPB + uu][b];
        z2 += zs[w][2 * UPB + uu][b];
        z3 += zs[w][3 * UPB + uu][b];
      }
      if (l == 0) {
        #pragma unroll
        for (int dd = 0; dd < 3; ++dd) {
          float xv = p.xT0[(t * 3 + dd) * B64 + b];
          z0 += xv * p.Wx0[dd * G1600 + 0 * U400 + u];
          z1 += xv * p.Wx0[dd * G1600 + 1 * U400 + u];
          z2 += xv * p.Wx0[dd * G1600 + 2 * U400 + u];
          z3 += xv * p.Wx0[dd * G1600 + 3 * U400 + u];
        }
      }
      float cp = creg;
      float ig = 1.f / (1.f + expf(-(z0 + pi[u] * cp)));
      float fg = 1.f / (1.f + expf(-(z1 + pf[u] * cp)));
      float gg = tanhf(z2);
      float cn = fg * cp + ig * gg;
      float og = 1.f / (1.f + expf(-(z3 + po[u] * cn)));
      creg = cn;
      float h = og * tanhf(cn);
      stg_c(&ownb[(size_t)(t & ownmask) * (U400 * B64) + (size_t)u * B64 + b], h);
    }

    // drain: every wave's s_waitcnt vmcnt(0) before s_barrier -> all sc1
    // h-stores acked at the coherence point before the arrive RMW below.
    __syncthreads();

    // ---- arrive (monotone accumulator; no resets) ----
    if (threadIdx.x == 0) {
      unsigned old = __hip_atomic_fetch_add(&acc_[l], 1u, __ATOMIC_RELAXED,
                                            __HIP_MEMORY_SCOPE_AGENT);
      if (old == (unsigned)((t + 1) * NBPL - 1))
        __hip_atomic_store(&cnt[l], (unsigned)(t + 1), __ATOMIC_RELAXED,
                           __HIP_MEMORY_SCOPE_AGENT);
    }
  }
}

// out[b][t][f] = bd[f] + sum_u h2[t][u][b] * Wd[u][f]
__launch_bounds__(256)
__global__ void dense_k(const float* __restrict__ h2, const float* __restrict__ Wd,
                        const float* __restrict__ bd, float* __restrict__ out) {
  int wid  = blockIdx.x * 4 + (threadIdx.x >> 6);
  int lane = threadIdx.x & 63;
  int t = wid / 3, f = wid - t * 3;
  if (t >= TT) return;
  float acc = bd[f];
  const float* hrow = h2 + (size_t)t * U400 * B64 + lane;
  #pragma unroll 4
  for (int u = 0; u < U400; ++u) acc += hrow[(size_t)u * B64] * Wd[u * 3 + f];
  out[((size_t)lane * TT + t) * 3 + f] = acc;
}

extern "C" void kernel_launch(void* const* d_in, const int* in_sizes, int n_in,
                              void* d_out, int out_size, void* d_ws, size_t ws_size,
                              hipStream_t stream) {
  const float* x   = (const float*)d_in[0];
  const float* Wx0 = (const float*)d_in[1];
  const float* Wh0 = (const float*)d_in[2];
  const float* pi0 = (const float*)d_in[3];
  const float* pf0 = (const float*)d_in[4];
  const float* po0 = (const float*)d_in[5];
  const float* b0  = (const float*)d_in[6];
  const float* Wx1 = (const float*)d_in[7];
  const float* Wh1 = (const float*)d_in[8];
  const float* pi1 = (const float*)d_in[9];
  const float* pf1 = (const float*)d_in[10];
  const float* po1 = (const float*)d_in[11];
  const float* b1  = (const float*)d_in[12];
  const float* Wx2 = (const float*)d_in[13];
  const float* Wh2 = (const float*)d_in[14];
  const float* pi2 = (const float*)d_in[15];
  const float* pf2 = (const float*)d_in[16];
  const float* po2 = (const float*)d_in[17];
  const float* b2  = (const float*)d_in[18];
  const float* Wd  = (const float*)d_in[19];
  const float* bd  = (const float*)d_in[20];

  float* ws   = (float*)d_ws;
  float* xT0  = ws;                  // 98304
  float* WhT0 = xT0  + 98304;        // 640000 each
  float* WhT1 = WhT0 + 640000;
  float* WhT2 = WhT1 + 640000;
  float* WxT1 = WhT2 + 640000;
  float* WxT2 = WxT1 + 640000;
  float* h0r  = WxT2 + 640000;       // 8*400*64 = 204800
  float* h1r  = h0r  + 204800;       // 204800
  float* h2   = h1r  + 204800;       // 13107200
  unsigned* syn = (unsigned*)(h2 + 13107200);  // 6 counters

  hipMemsetAsync(syn, 0, 64, stream);

  hipLaunchKernelGGL(xpose_x_k, dim3(384), dim3(256), 0, stream, x, xT0);

  dim3 tb(32, 8);
  dim3 tg((G1600 + 31) / 32, (U400 + 31) / 32);
  hipLaunchKernelGGL(transpose_k, tg, tb, 0, stream, Wh0, WhT0, U400, G1600);
  hipLaunchKernelGGL(transpose_k, tg, tb, 0, stream, Wh1, WhT1, U400, G1600);
  hipLaunchKernelGGL(transpose_k, tg, tb, 0, stream, Wh2, WhT2, U400, G1600);
  hipLaunchKernelGGL(transpose_k, tg, tb, 0, stream, Wx1, WxT1, U400, G1600);
  hipLaunchKernelGGL(transpose_k, tg, tb, 0, stream, Wx2, WxT2, U400, G1600);

  ScanP hp;
  hp.xT0 = xT0;  hp.Wx0 = Wx0;
  hp.WxT1 = WxT1; hp.WxT2 = WxT2;
  hp.WhT0 = WhT0; hp.WhT1 = WhT1; hp.WhT2 = WhT2;
  hp.b0 = b0; hp.b1 = b1; hp.b2 = b2;
  hp.pi0 = pi0; hp.pi1 = pi1; hp.pi2 = pi2;
  hp.pf0 = pf0; hp.pf1 = pf1; hp.pf2 = pf2;
  hp.po0 = po0; hp.po1 = po1; hp.po2 = po2;
  hp.h0r = h0r; hp.h1r = h1r; hp.h2 = h2;
  hp.sync = syn;

  // cooperative launch only for the co-residency guarantee (no grid.sync used)
  void* args[] = { &hp };
  hipLaunchCooperativeKernel((void*)lstm_scan_k, dim3(NBLK), dim3(NTHR),
                             args, 0, stream);

  hipLaunchKernelGGL(dense_k, dim3(384), dim3(256), 0, stream, h2, Wd, bd,
                     (float*)d_out);
}